// Round 14
// baseline (31.919 us; speedup 1.0000x reference)
//
#include <hip/hip_runtime.h>
#include <math.h>

#define NN 1024
#define NBB 16
#define NP 256
#define TT 80
#define EPS_LEN 1e-9f
#define EPS_DD 1e-12f

__device__ __forceinline__ float frcp(float x){ return __builtin_amdgcn_rcpf(x); }
__device__ __forceinline__ float fsq(float x){ return __builtin_amdgcn_sqrtf(x); }
__device__ __forceinline__ float rlane_f(float x, int l){
  return __builtin_bit_cast(float, __builtin_amdgcn_readlane(__builtin_bit_cast(int, x), l));
}
// count(c <= v) == count(c < bump(v)) exactly for nonneg floats
__device__ __forceinline__ float bump(float v){
  return __builtin_bit_cast(float, __builtin_bit_cast(int, v) + 1);
}

// ---- DPP wave64 primitives (validated R6-R11) ----
template<int CTRL,int RM>
__device__ __forceinline__ float dpp_add(float v){
  int t = __builtin_amdgcn_update_dpp(0, __builtin_bit_cast(int, v), CTRL, RM, 0xf, true);
  return v + __builtin_bit_cast(float, t);
}
__device__ __forceinline__ float wave_incl_scan(float v){
  v = dpp_add<0x111,0xf>(v);
  v = dpp_add<0x112,0xf>(v);
  v = dpp_add<0x114,0xf>(v);
  v = dpp_add<0x118,0xf>(v);
  v = dpp_add<0x142,0xa>(v);
  v = dpp_add<0x143,0xc>(v);
  return v;
}
__device__ __forceinline__ float wave_sum(float v){ return rlane_f(wave_incl_scan(v), 63); }
template<int CTRL,int RM>
__device__ __forceinline__ float dpp_min(float v){
  int t = __builtin_amdgcn_update_dpp(0x7f800000, __builtin_bit_cast(int,v), CTRL, RM, 0xf, false);
  return fminf(v, __builtin_bit_cast(float,t));
}
__device__ __forceinline__ float wave_min_all(float v){
  v=dpp_min<0x111,0xf>(v); v=dpp_min<0x112,0xf>(v);
  v=dpp_min<0x114,0xf>(v); v=dpp_min<0x118,0xf>(v);
  v=dpp_min<0x142,0xa>(v); v=dpp_min<0x143,0xc>(v);
  return rlane_f(v, 63);
}

// Wave-synchronous LDS fence (own-region write->read ordering).
__device__ __forceinline__ void lds_fence() {
  __builtin_amdgcn_wave_barrier();
  asm volatile("s_waitcnt lgkmcnt(0)" ::: "memory");
  __builtin_amdgcn_wave_barrier();
}

// n_valid, wave-wide. Mask layout auto-detect: byte[1] != 0 -> bool bytes.
__device__ __forceinline__ int wave_nv(const void* mask, size_t base, int lane) {
  bool as_byte = ((const unsigned char*)mask)[1] != 0;
  int nv = 0;
  if (as_byte) {
    uchar4 v = ((const uchar4*)((const unsigned char*)mask + base))[lane];
    nv += __popcll(__ballot(v.x != 0));
    nv += __popcll(__ballot(v.y != 0));
    nv += __popcll(__ballot(v.z != 0));
    nv += __popcll(__ballot(v.w != 0));
  } else {
    int4 v = ((const int4*)((const int*)mask + base))[lane];
    nv += __popcll(__ballot(v.x != 0));
    nv += __popcll(__ballot(v.y != 0));
    nv += __popcll(__ballot(v.z != 0));
    nv += __popcll(__ballot(v.w != 0));
  }
  return nv;
}

// Count entries in cs[0..255] strictly < v.
// co[32] wave-uniform coarse table, co[k] = cs[8k+7]; fine bucket = 8 entries
// (2 x b128 = 32B/lane). Bit-identical count to the 16-bucket version.
__device__ __forceinline__ int count256s(const float* __restrict__ cs,
                                         const float* co, float v){
  int K = 0;
  #pragma unroll
  for (int k=0;k<32;k++) K += (co[k] < v);
  int base = (K < 32 ? K : 31) * 8;
  const float4* f4 = (const float4*)(cs + base);
  float4 c0=f4[0], c1=f4[1];
  int r = (c0.x<v)+(c0.y<v)+(c0.z<v)+(c0.w<v)
        + (c1.x<v)+(c1.y<v)+(c1.z<v)+(c1.w<v);
  return (K >= 32) ? 256 : (base + r);
}

struct SegOut {
  float cpre[4];
  float run;
  float bdf, btf; int bjf;
  float bdl, btl; int bjl;
};

template<bool NEEDMIN>
__device__ __forceinline__ void seg_pass(float4 A, float4 B, float4 C,
                                         int lane, int nv,
                                         float p0x, float p0y, float p0z,
                                         float* __restrict__ pts, SegOut& R) {
  const int j0 = lane * 4;
  float x[5], y[5], z[5];
  x[0]=A.x; y[0]=A.y; z[0]=A.z;
  x[1]=A.w; y[1]=B.x; z[1]=B.y;
  x[2]=B.z; y[2]=B.w; z[2]=C.x;
  x[3]=C.y; y[3]=C.z; z[3]=C.w;
  x[4]=__shfl_down(x[0],1,64); y[4]=__shfl_down(y[0],1,64); z[4]=__shfl_down(z[0],1,64);
  ((float4*)pts)[lane*3+0] = make_float4(x[0],y[0],z[0],x[1]);
  ((float4*)pts)[lane*3+1] = make_float4(y[1],z[1],x[2],y[2]);
  ((float4*)pts)[lane*3+2] = make_float4(z[2],x[3],y[3],z[3]);
  float run = 0.f;
  R.bdf=INFINITY; R.btf=0.f; R.bjf=j0;
  R.bdl=INFINITY; R.btl=0.f; R.bjl=j0;
  #pragma unroll
  for (int k=0;k<4;k++){
    bool valid = (j0+k) < nv-1;
    float vx=x[k+1]-x[k], vy=y[k+1]-y[k], vz=z[k+1]-z[k];
    float n2 = vx*vx+vy*vy+vz*vz;
    float sl = valid ? fmaxf(fsq(n2), EPS_LEN) : 0.f;
    if (NEEDMIN){
      float t = ((p0x-x[k])*vx+(p0y-y[k])*vy+(p0z-z[k])*vz) * frcp(fmaxf(n2,EPS_DD));
      t = fminf(fmaxf(t,0.f),1.f);
      float qx=x[k]+t*vx, qy=y[k]+t*vy, qz=z[k]+t*vz;
      float dx=p0x-qx, dy=p0y-qy, dz=p0z-qz;
      float d2 = valid ? (dx*dx+dy*dy+dz*dz) : INFINITY;
      if (d2 <  R.bdf){R.bdf=d2; R.bjf=j0+k; R.btf=t;}
      if (d2 <= R.bdl){R.bdl=d2; R.bjl=j0+k; R.btl=t;}
    }
    run += sl; R.cpre[k]=run;
  }
  R.run = run;
}

__device__ __forceinline__ void cs_pair_from_regs(int idx, float ex, const SegOut& R,
                                                  float& c0, float& c1){
  int o = idx >> 2, r = idx & 3;
  float a0 = (r==0)?0.f : (r==1)?R.cpre[0] : (r==2)?R.cpre[1] : R.cpre[2];
  float a1 = (r==0)?R.cpre[0] : (r==1)?R.cpre[1] : (r==2)?R.cpre[2] : R.run;
  c0 = rlane_f(ex + a0, o);
  c1 = rlane_f(ex + a1, o);
}

// Unified fwd/rev timestep interpolation (single strict count).
__device__ __forceinline__ void interp_at(const float* __restrict__ pts,
                                          const float* __restrict__ cs,
                                          const float* co, float Tot, int nv, int jmaxv,
                                          int dir, float ts,
                                          float& prx, float& pry, float& prz){
  float vq = dir ? (Tot - ts) : bump(ts);
  int cnt = count256s(cs, co, vq);
  int j = dir ? (nv-1-cnt) : (cnt-1);
  j = j<0?0:(j>jmaxv?jmaxv:j);
  int ia = dir ? (nv-1-j) : j;
  int ib = dir ? (nv-2-j) : (j+1);
  int lo = dir ? ib : ia;
  float c_lo = cs[lo], c_hi = cs[lo+1];
  float base = dir ? (Tot - c_hi) : c_lo;
  float tl = (ts - base) * frcp(fmaxf(c_hi - c_lo, EPS_LEN));
  tl = fminf(fmaxf(tl,0.f),1.f);
  float3 PA = *(const float3*)(pts + ia*3);
  float3 PB = *(const float3*)(pts + ib*3);
  prx = PA.x + tl*(PB.x-PA.x);
  pry = PA.y + tl*(PB.y-PA.y);
  prz = PA.z + tl*(PB.z-PA.z);
}

// tcs[i] from this wave's trajectory scan registers (no LDS).
// MUST be called with full EXEC: uses cross-lane shuffles.
__device__ __forceinline__ float tc_of(int i, float exclA, float totA, float tBv){
  float vA = __shfl(exclA, i, 64);
  float vB = __shfl(tBv, i - 65, 64);
  return (i < 64) ? vA : ((i == 64) ? totA : vB);
}

// Single fused kernel. Block = one n, 16 waves x 1 candidate. Winner phase
// reads the winning candidate's resident LDS region -- no recompute.
__global__ __launch_bounds__(1024, 8)
void fused_all(const float* __restrict__ traj, const float* __restrict__ rp,
               const void* __restrict__ mask, float* __restrict__ ws,
               float* __restrict__ out) {
  __shared__ float s_pts[NBB][NP*3];   // 48 KB
  __shared__ float s_cs[NBB][NP];      // 16 KB  (total exactly 64 KB)

  const int wid = threadIdx.x>>6, lane = threadIdx.x&63;
  const int n = blockIdx.x;
  const float* pos = traj + (size_t)n*TT*3;
  float* wcost = ws + (size_t)n*96;    // 32 cost | 32 ent | 16 tot | 16 nv
  float* went  = wcost + 32;
  float* wtot  = wcost + 64;
  int*   wnv   = (int*)(wcost + 80);

  // ---- trajectory cum-arc-length in registers (identical across waves) ----
  float3 ptl, pB;
  ptl.x=pos[lane*3+0]; ptl.y=pos[lane*3+1]; ptl.z=pos[lane*3+2];
  pB = make_float3(0.f,0.f,0.f);
  if (lane < 16){
    int t = 64+lane;
    pB.x=pos[t*3+0]; pB.y=pos[t*3+1]; pB.z=pos[t*3+2];
  }
  float nx=__shfl_down(ptl.x,1,64), ny=__shfl_down(ptl.y,1,64), nz=__shfl_down(ptl.z,1,64);
  if (lane==63){ nx=rlane_f(pB.x,0); ny=rlane_f(pB.y,0); nz=rlane_f(pB.z,0); }
  float dxa=nx-ptl.x, dya=ny-ptl.y, dza=nz-ptl.z;
  float segA = fsq(dxa*dxa+dya*dya+dza*dza);
  float mx=__shfl_down(pB.x,1,64), my=__shfl_down(pB.y,1,64), mz=__shfl_down(pB.z,1,64);
  float exb=mx-pB.x, eyb=my-pB.y, ezb=mz-pB.z;
  float segB = (lane<15) ? fsq(exb*exb+eyb*eyb+ezb*ezb) : 0.f;
  float incA = wave_incl_scan(segA);
  float exclA = incA - segA;           // exclA[0] == 0 exactly
  float totA = rlane_f(incA, 63);
  float tBv = totA + wave_incl_scan(segB);
  const float p0x = rlane_f(ptl.x,0), p0y = rlane_f(ptl.y,0), p0z = rlane_f(ptl.z,0);

  // ---- candidate eval: wave wid owns boundary b = wid ----
  const int b = wid;
  const size_t nb = (size_t)n*NBB + b;
  const float4* p4 = (const float4*)(rp + nb*NP*3);
  float4 A = p4[lane*3+0], Bq = p4[lane*3+1], Cq = p4[lane*3+2];
  int nv = wave_nv(mask, nb*NP, lane);
  float* pts = s_pts[wid];
  float* csb = s_cs[wid];
  float cf=INFINITY, cr=INFINITY, e0=0.f, e1=0.f, Tot=0.f;

  if (nv >= 2){
    SegOut R;
    seg_pass<true>(A,Bq,Cq, lane, nv, p0x,p0y,p0z, pts, R);
    float inc = wave_incl_scan(R.run);
    float ex = inc - R.run;
    ((float4*)csb)[lane] = make_float4(ex, ex+R.cpre[0], ex+R.cpre[1], ex+R.cpre[2]);
    Tot = rlane_f(inc, 63);
    // co32[k] = cs[8k+7] = (ex + cpre[2]) at lane 2k+1  (wave-uniform)
    float cval = ex + R.cpre[2];
    float co[32];
    #pragma unroll
    for (int k=0;k<32;k++) co[k] = rlane_f(cval, 2*k+1);
    float minv = wave_min_all(R.bdf);
    unsigned long long mf = __ballot(R.bdf == minv);
    unsigned long long ml = __ballot(R.bdl == minv);
    int lf = __builtin_ctzll(mf);
    int ll = 63 - __builtin_clzll(ml);
    int   jf = __builtin_amdgcn_readlane(R.bjf, lf);
    float tf = rlane_f(R.btf, lf);
    int   jl = __builtin_amdgcn_readlane(R.bjl, ll);
    float tl0 = rlane_f(R.btl, ll);
    float cjf, cjf1, cjl, cjl1;
    cs_pair_from_regs(jf, ex, R, cjf, cjf1);
    cs_pair_from_regs(jl, ex, R, cjl, cjl1);
    e0 = cjf + tf*(cjf1-cjf);
    e1 = (Tot - cjl1) + (1.f-tl0)*(cjl1-cjl);

    lds_fence();   // own pts/cs writes -> cross-lane reads below

    const int jmaxv = nv-2;
    float accf=0.f, accr=0.f;
    #pragma unroll
    for (int p=0;p<3;p++){
      int task = p*64 + lane;
      bool act = task < 2*TT;
      int dir = task>=TT ? 1 : 0;
      int t = dir ? task-TT : task;
      int tr = t < TT ? t : TT-1;
      // full-EXEC: tc_of uses shuffles -- must run on ALL lanes (R12 bug fix)
      float tcv = tc_of(tr, exclA, totA, tBv);
      float ts = (dir ? e1 : e0) + tcv;
      ts = fminf(fmaxf(ts,0.f),Tot);
      if (act){                 // lane-local LDS work only on active lanes
        float prx,pry,prz;
        interp_at(pts, csb, co, Tot, nv, jmaxv, dir, ts, prx,pry,prz);
        if (p==0){
          float dx=ptl.x-prx, dy=ptl.y-pry, dz=ptl.z-prz;    // t==lane
          accf += fsq(dx*dx+dy*dy+dz*dz);
        } else {
          float px_, py_, pz_;
          if (p==1 && !dir){ px_=pB.x; py_=pB.y; pz_=pB.z; }  // t==64+lane
          else { px_=pos[t*3+0]; py_=pos[t*3+1]; pz_=pos[t*3+2]; }
          float dx=px_-prx, dy=py_-pry, dz=pz_-prz;
          float dd=fsq(dx*dx+dy*dy+dz*dz);
          if (dir) accr+=dd; else accf+=dd;
        }
      }
    }
    cf = wave_sum(accf); cr = wave_sum(accr);
  }
  if (lane==0){
    wcost[b*2+0]=cf; wcost[b*2+1]=cr;
    went [b*2+0]=e0; went [b*2+1]=e1;
    wtot[b]=Tot; wnv[b]=nv;
  }

  __syncthreads();   // drains global stores + makes LDS block-visible
  if (wid != 0) return;

  // ---- winner phase: wave 0 only; zero recompute ----
  float bc = (lane < NBB*2)
    ? __hip_atomic_load(&wcost[lane], __ATOMIC_RELAXED, __HIP_MEMORY_SCOPE_AGENT)
    : INFINITY;
  int bi = (lane < NBB*2) ? lane : 64;
  #pragma unroll
  for (int d=1;d<64;d<<=1){
    float oc=__shfl_xor(bc,d,64); int oi=__shfl_xor(bi,d,64);
    if (oc<bc || (oc==bc && oi<bi)){bc=oc;bi=oi;}
  }
  float* o = out + (size_t)n*TT*3;
  if (bc == INFINITY){   // no valid candidate: passthrough
    if (lane < 60) ((float4*)o)[lane] = ((const float4*)pos)[lane];
    return;
  }
  int wb = bi>>1, dir = bi&1;
  float entry = __hip_atomic_load(&went[bi], __ATOMIC_RELAXED, __HIP_MEMORY_SCOPE_AGENT);
  float TotW  = __hip_atomic_load(&wtot[wb], __ATOMIC_RELAXED, __HIP_MEMORY_SCOPE_AGENT);
  int   nvW   = __hip_atomic_load(&wnv[wb],  __ATOMIC_RELAXED, __HIP_MEMORY_SCOPE_AGENT);
  const float* ptsW = s_pts[wb];
  const float* csW  = s_cs[wb];
  float cobk = (lane<32) ? csW[lane*8+7] : 0.f;
  float coW[32];
  #pragma unroll
  for (int k=0;k<32;k++) coW[k] = rlane_f(cobk, k);
  const int jmaxv = nvW-2;
  #pragma unroll
  for (int p=0;p<2;p++){
    int t = p*64 + lane;
    int tr = t < TT ? t : TT-1;
    // full-EXEC shuffle fetch, then predicate the lane-local work
    float tcv = tc_of(tr, exclA, totA, tBv);
    if (t < TT){
      float ts = entry + tcv;
      ts = fminf(fmaxf(ts,0.f),TotW);
      float prx,pry,prz;
      interp_at(ptsW, csW, coW, TotW, nvW, jmaxv, dir, ts, prx,pry,prz);
      o[t*3+0]=prx; o[t*3+1]=pry; o[t*3+2]=prz;
    }
  }
}

extern "C" void kernel_launch(void* const* d_in, const int* in_sizes, int n_in,
                              void* d_out, int out_size, void* d_ws, size_t ws_size,
                              hipStream_t stream) {
  const float* traj = (const float*)d_in[0];
  const float* rp   = (const float*)d_in[1];
  const void*  mask = d_in[2];
  float* ws   = (float*)d_ws;      // NN*96 floats
  float* out  = (float*)d_out;
  hipLaunchKernelGGL(fused_all, dim3(NN), dim3(1024), 0, stream,
                     traj, rp, mask, ws, out);
}

// Round 15
// 30.334 us; speedup vs baseline: 1.0523x; 1.0523x over previous
//
#include <hip/hip_runtime.h>
#include <math.h>

#define NN 1024
#define NBB 16
#define NP 256
#define TT 80
#define EPS_LEN 1e-9f
#define EPS_DD 1e-12f

__device__ __forceinline__ float frcp(float x){ return __builtin_amdgcn_rcpf(x); }
__device__ __forceinline__ float fsq(float x){ return __builtin_amdgcn_sqrtf(x); }
__device__ __forceinline__ float rlane_f(float x, int l){
  return __builtin_bit_cast(float, __builtin_amdgcn_readlane(__builtin_bit_cast(int, x), l));
}
// count(c <= v) == count(c < bump(v)) exactly for nonneg floats
__device__ __forceinline__ float bump(float v){
  return __builtin_bit_cast(float, __builtin_bit_cast(int, v) + 1);
}

// ---- DPP wave64 primitives (validated R6-R11) ----
template<int CTRL,int RM>
__device__ __forceinline__ float dpp_add(float v){
  int t = __builtin_amdgcn_update_dpp(0, __builtin_bit_cast(int, v), CTRL, RM, 0xf, true);
  return v + __builtin_bit_cast(float, t);
}
__device__ __forceinline__ float wave_incl_scan(float v){
  v = dpp_add<0x111,0xf>(v);
  v = dpp_add<0x112,0xf>(v);
  v = dpp_add<0x114,0xf>(v);
  v = dpp_add<0x118,0xf>(v);
  v = dpp_add<0x142,0xa>(v);
  v = dpp_add<0x143,0xc>(v);
  return v;
}
__device__ __forceinline__ float wave_sum(float v){ return rlane_f(wave_incl_scan(v), 63); }
template<int CTRL,int RM>
__device__ __forceinline__ float dpp_min(float v){
  int t = __builtin_amdgcn_update_dpp(0x7f800000, __builtin_bit_cast(int,v), CTRL, RM, 0xf, false);
  return fminf(v, __builtin_bit_cast(float,t));
}
__device__ __forceinline__ float wave_min_all(float v){
  v=dpp_min<0x111,0xf>(v); v=dpp_min<0x112,0xf>(v);
  v=dpp_min<0x114,0xf>(v); v=dpp_min<0x118,0xf>(v);
  v=dpp_min<0x142,0xa>(v); v=dpp_min<0x143,0xc>(v);
  return rlane_f(v, 63);
}

// Wave-synchronous LDS fence (own-region write->read ordering).
__device__ __forceinline__ void lds_fence() {
  __builtin_amdgcn_wave_barrier();
  asm volatile("s_waitcnt lgkmcnt(0)" ::: "memory");
  __builtin_amdgcn_wave_barrier();
}

// n_valid, wave-wide. Mask layout auto-detect: byte[1] != 0 -> bool bytes.
__device__ __forceinline__ int wave_nv(const void* mask, size_t base, int lane) {
  bool as_byte = ((const unsigned char*)mask)[1] != 0;
  int nv = 0;
  if (as_byte) {
    uchar4 v = ((const uchar4*)((const unsigned char*)mask + base))[lane];
    nv += __popcll(__ballot(v.x != 0));
    nv += __popcll(__ballot(v.y != 0));
    nv += __popcll(__ballot(v.z != 0));
    nv += __popcll(__ballot(v.w != 0));
  } else {
    int4 v = ((const int4*)((const int*)mask + base))[lane];
    nv += __popcll(__ballot(v.x != 0));
    nv += __popcll(__ballot(v.y != 0));
    nv += __popcll(__ballot(v.z != 0));
    nv += __popcll(__ballot(v.w != 0));
  }
  return nv;
}

// Count entries in cs[0..255] strictly < v; co[16] wave-uniform coarse table.
__device__ __forceinline__ int count256s(const float* __restrict__ cs,
                                         const float* co, float v){
  int K = 0;
  #pragma unroll
  for (int k=0;k<16;k++) K += (co[k] < v);
  int base = (K < 16 ? K : 15) * 16;
  const float4* f4 = (const float4*)(cs + base);
  float4 c0=f4[0], c1=f4[1], c2=f4[2], c3=f4[3];
  int r = (c0.x<v)+(c0.y<v)+(c0.z<v)+(c0.w<v)+(c1.x<v)+(c1.y<v)+(c1.z<v)+(c1.w<v)
        + (c2.x<v)+(c2.y<v)+(c2.z<v)+(c2.w<v)+(c3.x<v)+(c3.y<v)+(c3.z<v)+(c3.w<v);
  return (K >= 16) ? 256 : (base + r);
}

struct SegOut {
  float cpre[4];
  float run;
  float bdf, btf; int bjf;
  float bdl, btl; int bjl;
};

template<bool NEEDMIN>
__device__ __forceinline__ void seg_pass(float4 A, float4 B, float4 C,
                                         int lane, int nv,
                                         float p0x, float p0y, float p0z,
                                         float* __restrict__ pts, SegOut& R) {
  const int j0 = lane * 4;
  float x[5], y[5], z[5];
  x[0]=A.x; y[0]=A.y; z[0]=A.z;
  x[1]=A.w; y[1]=B.x; z[1]=B.y;
  x[2]=B.z; y[2]=B.w; z[2]=C.x;
  x[3]=C.y; y[3]=C.z; z[3]=C.w;
  x[4]=__shfl_down(x[0],1,64); y[4]=__shfl_down(y[0],1,64); z[4]=__shfl_down(z[0],1,64);
  ((float4*)pts)[lane*3+0] = make_float4(x[0],y[0],z[0],x[1]);
  ((float4*)pts)[lane*3+1] = make_float4(y[1],z[1],x[2],y[2]);
  ((float4*)pts)[lane*3+2] = make_float4(z[2],x[3],y[3],z[3]);
  float run = 0.f;
  R.bdf=INFINITY; R.btf=0.f; R.bjf=j0;
  R.bdl=INFINITY; R.btl=0.f; R.bjl=j0;
  #pragma unroll
  for (int k=0;k<4;k++){
    bool valid = (j0+k) < nv-1;
    float vx=x[k+1]-x[k], vy=y[k+1]-y[k], vz=z[k+1]-z[k];
    float n2 = vx*vx+vy*vy+vz*vz;
    float sl = valid ? fmaxf(fsq(n2), EPS_LEN) : 0.f;
    if (NEEDMIN){
      float t = ((p0x-x[k])*vx+(p0y-y[k])*vy+(p0z-z[k])*vz) * frcp(fmaxf(n2,EPS_DD));
      t = fminf(fmaxf(t,0.f),1.f);
      float qx=x[k]+t*vx, qy=y[k]+t*vy, qz=z[k]+t*vz;
      float dx=p0x-qx, dy=p0y-qy, dz=p0z-qz;
      float d2 = valid ? (dx*dx+dy*dy+dz*dz) : INFINITY;
      if (d2 <  R.bdf){R.bdf=d2; R.bjf=j0+k; R.btf=t;}
      if (d2 <= R.bdl){R.bdl=d2; R.bjl=j0+k; R.btl=t;}
    }
    run += sl; R.cpre[k]=run;
  }
  R.run = run;
}

__device__ __forceinline__ void cs_pair_from_regs(int idx, float ex, const SegOut& R,
                                                  float& c0, float& c1){
  int o = idx >> 2, r = idx & 3;
  float a0 = (r==0)?0.f : (r==1)?R.cpre[0] : (r==2)?R.cpre[1] : R.cpre[2];
  float a1 = (r==0)?R.cpre[0] : (r==1)?R.cpre[1] : (r==2)?R.cpre[2] : R.run;
  c0 = rlane_f(ex + a0, o);
  c1 = rlane_f(ex + a1, o);
}

// Unified fwd/rev timestep interpolation (single strict count).
__device__ __forceinline__ void interp_at(const float* __restrict__ pts,
                                          const float* __restrict__ cs,
                                          const float* co, float Tot, int nv, int jmaxv,
                                          int dir, float ts,
                                          float& prx, float& pry, float& prz){
  float vq = dir ? (Tot - ts) : bump(ts);
  int cnt = count256s(cs, co, vq);
  int j = dir ? (nv-1-cnt) : (cnt-1);
  j = j<0?0:(j>jmaxv?jmaxv:j);
  int ia = dir ? (nv-1-j) : j;
  int ib = dir ? (nv-2-j) : (j+1);
  int lo = dir ? ib : ia;
  float c_lo = cs[lo], c_hi = cs[lo+1];
  float base = dir ? (Tot - c_hi) : c_lo;
  float tl = (ts - base) * frcp(fmaxf(c_hi - c_lo, EPS_LEN));
  tl = fminf(fmaxf(tl,0.f),1.f);
  float3 PA = *(const float3*)(pts + ia*3);
  float3 PB = *(const float3*)(pts + ib*3);
  prx = PA.x + tl*(PB.x-PA.x);
  pry = PA.y + tl*(PB.y-PA.y);
  prz = PA.z + tl*(PB.z-PA.z);
}

// tcs[i] from this wave's trajectory scan registers (no LDS).
// MUST be called with full EXEC: uses cross-lane shuffles.
__device__ __forceinline__ float tc_of(int i, float exclA, float totA, float tBv){
  float vA = __shfl(exclA, i, 64);
  float vB = __shfl(tBv, i - 65, 64);
  return (i < 64) ? vA : ((i == 64) ? totA : vB);
}

// Single fused kernel. Block = one n, 16 waves x 1 candidate. Winner phase
// reads the winning candidate's resident LDS region -- no recompute.
__global__ __launch_bounds__(1024, 8)
void fused_all(const float* __restrict__ traj, const float* __restrict__ rp,
               const void* __restrict__ mask, float* __restrict__ ws,
               float* __restrict__ out) {
  __shared__ float s_pts[NBB][NP*3];   // 48 KB
  __shared__ float s_cs[NBB][NP];      // 16 KB  (total exactly 64 KB)

  const int wid = threadIdx.x>>6, lane = threadIdx.x&63;
  const int n = blockIdx.x;
  const float* pos = traj + (size_t)n*TT*3;
  float* wcost = ws + (size_t)n*96;    // 32 cost | 32 ent | 16 tot | 16 nv
  float* went  = wcost + 32;
  float* wtot  = wcost + 64;
  int*   wnv   = (int*)(wcost + 80);

  // ---- trajectory cum-arc-length in registers (identical across waves) ----
  float3 ptl, pB;
  ptl.x=pos[lane*3+0]; ptl.y=pos[lane*3+1]; ptl.z=pos[lane*3+2];
  pB = make_float3(0.f,0.f,0.f);
  if (lane < 16){
    int t = 64+lane;
    pB.x=pos[t*3+0]; pB.y=pos[t*3+1]; pB.z=pos[t*3+2];
  }
  float nx=__shfl_down(ptl.x,1,64), ny=__shfl_down(ptl.y,1,64), nz=__shfl_down(ptl.z,1,64);
  if (lane==63){ nx=rlane_f(pB.x,0); ny=rlane_f(pB.y,0); nz=rlane_f(pB.z,0); }
  float dxa=nx-ptl.x, dya=ny-ptl.y, dza=nz-ptl.z;
  float segA = fsq(dxa*dxa+dya*dya+dza*dza);
  float mx=__shfl_down(pB.x,1,64), my=__shfl_down(pB.y,1,64), mz=__shfl_down(pB.z,1,64);
  float exb=mx-pB.x, eyb=my-pB.y, ezb=mz-pB.z;
  float segB = (lane<15) ? fsq(exb*exb+eyb*eyb+ezb*ezb) : 0.f;
  float incA = wave_incl_scan(segA);
  float exclA = incA - segA;           // exclA[0] == 0 exactly
  float totA = rlane_f(incA, 63);
  float tBv = totA + wave_incl_scan(segB);
  const float p0x = rlane_f(ptl.x,0), p0y = rlane_f(ptl.y,0), p0z = rlane_f(ptl.z,0);

  // ---- candidate eval: wave wid owns boundary b = wid ----
  const int b = wid;
  const size_t nb = (size_t)n*NBB + b;
  const float4* p4 = (const float4*)(rp + nb*NP*3);
  float4 A = p4[lane*3+0], Bq = p4[lane*3+1], Cq = p4[lane*3+2];
  int nv = wave_nv(mask, nb*NP, lane);
  float* pts = s_pts[wid];
  float* csb = s_cs[wid];
  float cf=INFINITY, cr=INFINITY, e0=0.f, e1=0.f, Tot=0.f;

  if (nv >= 2){
    SegOut R;
    seg_pass<true>(A,Bq,Cq, lane, nv, p0x,p0y,p0z, pts, R);
    float inc = wave_incl_scan(R.run);
    float ex = inc - R.run;
    ((float4*)csb)[lane] = make_float4(ex, ex+R.cpre[0], ex+R.cpre[1], ex+R.cpre[2]);
    Tot = rlane_f(inc, 63);
    float cval = ex + R.cpre[2];
    float co[16];
    #pragma unroll
    for (int k=0;k<16;k++) co[k] = rlane_f(cval, 4*k+3);
    float minv = wave_min_all(R.bdf);
    unsigned long long mf = __ballot(R.bdf == minv);
    unsigned long long ml = __ballot(R.bdl == minv);
    int lf = __builtin_ctzll(mf);
    int ll = 63 - __builtin_clzll(ml);
    int   jf = __builtin_amdgcn_readlane(R.bjf, lf);
    float tf = rlane_f(R.btf, lf);
    int   jl = __builtin_amdgcn_readlane(R.bjl, ll);
    float tl0 = rlane_f(R.btl, ll);
    float cjf, cjf1, cjl, cjl1;
    cs_pair_from_regs(jf, ex, R, cjf, cjf1);
    cs_pair_from_regs(jl, ex, R, cjl, cjl1);
    e0 = cjf + tf*(cjf1-cjf);
    e1 = (Tot - cjl1) + (1.f-tl0)*(cjl1-cjl);

    lds_fence();   // own pts/cs writes -> cross-lane reads below

    const int jmaxv = nv-2;
    float accf=0.f, accr=0.f;
    #pragma unroll
    for (int p=0;p<3;p++){
      int task = p*64 + lane;
      bool act = task < 2*TT;
      int dir = task>=TT ? 1 : 0;
      int t = dir ? task-TT : task;
      int tr = t < TT ? t : TT-1;
      float ts = (dir ? e1 : e0) + tc_of(tr, exclA, totA, tBv);
      ts = fminf(fmaxf(ts,0.f),Tot);
      float prx,pry,prz;
      interp_at(pts, csb, co, Tot, nv, jmaxv, dir, ts, prx,pry,prz);
      if (p==0){
        float dx=ptl.x-prx, dy=ptl.y-pry, dz=ptl.z-prz;    // t==lane
        accf += fsq(dx*dx+dy*dy+dz*dz);
      } else if (act){
        float px_, py_, pz_;
        if (p==1 && !dir){ px_=pB.x; py_=pB.y; pz_=pB.z; }  // t==64+lane
        else { px_=pos[t*3+0]; py_=pos[t*3+1]; pz_=pos[t*3+2]; }
        float dx=px_-prx, dy=py_-pry, dz=pz_-prz;
        float dd=fsq(dx*dx+dy*dy+dz*dz);
        if (dir) accr+=dd; else accf+=dd;
      }
    }
    cf = wave_sum(accf); cr = wave_sum(accr);
  }
  if (lane==0){
    wcost[b*2+0]=cf; wcost[b*2+1]=cr;
    went [b*2+0]=e0; went [b*2+1]=e1;
    wtot[b]=Tot; wnv[b]=nv;
  }

  __syncthreads();   // drains global stores (vmcnt 0) + makes LDS block-visible
  if (wid != 0) return;

  // ---- winner phase: wave 0 only; zero recompute ----
  float bc = (lane < NBB*2)
    ? __hip_atomic_load(&wcost[lane], __ATOMIC_RELAXED, __HIP_MEMORY_SCOPE_AGENT)
    : INFINITY;
  int bi = (lane < NBB*2) ? lane : 64;
  #pragma unroll
  for (int d=1;d<64;d<<=1){
    float oc=__shfl_xor(bc,d,64); int oi=__shfl_xor(bi,d,64);
    if (oc<bc || (oc==bc && oi<bi)){bc=oc;bi=oi;}
  }
  float* o = out + (size_t)n*TT*3;
  if (bc == INFINITY){   // no valid candidate: passthrough
    if (lane < 60) ((float4*)o)[lane] = ((const float4*)pos)[lane];
    return;
  }
  int wb = bi>>1, dir = bi&1;
  float entry = __hip_atomic_load(&went[bi], __ATOMIC_RELAXED, __HIP_MEMORY_SCOPE_AGENT);
  float TotW  = __hip_atomic_load(&wtot[wb], __ATOMIC_RELAXED, __HIP_MEMORY_SCOPE_AGENT);
  int   nvW   = __hip_atomic_load(&wnv[wb],  __ATOMIC_RELAXED, __HIP_MEMORY_SCOPE_AGENT);
  const float* ptsW = s_pts[wb];
  const float* csW  = s_cs[wb];
  float cobk = (lane<16) ? csW[lane*16+15] : 0.f;
  float coW[16];
  #pragma unroll
  for (int k=0;k<16;k++) coW[k] = rlane_f(cobk, k);
  const int jmaxv = nvW-2;
  #pragma unroll
  for (int p=0;p<2;p++){
    int t = p*64 + lane;
    if (t < TT){
      float ts = entry + tc_of(t, exclA, totA, tBv);
      ts = fminf(fmaxf(ts,0.f),TotW);
      float prx,pry,prz;
      interp_at(ptsW, csW, coW, TotW, nvW, jmaxv, dir, ts, prx,pry,prz);
      o[t*3+0]=prx; o[t*3+1]=pry; o[t*3+2]=prz;
    }
  }
}

extern "C" void kernel_launch(void* const* d_in, const int* in_sizes, int n_in,
                              void* d_out, int out_size, void* d_ws, size_t ws_size,
                              hipStream_t stream) {
  const float* traj = (const float*)d_in[0];
  const float* rp   = (const float*)d_in[1];
  const void*  mask = d_in[2];
  float* ws   = (float*)d_ws;      // NN*96 floats
  float* out  = (float*)d_out;
  hipLaunchKernelGGL(fused_all, dim3(NN), dim3(1024), 0, stream,
                     traj, rp, mask, ws, out);
}